// Round 9
// baseline (341.054 us; speedup 1.0000x reference)
//
#include <hip/hip_runtime.h>

// SLAYER 3-layer CUBA SNN — i8 3-plane MFMA GEMM + fused leaky-IF scan.
// R28 = R27 resubmitted verbatim (R27's bench was an infra failure: "MI355X
// container failed twice" — no compile/test/counter evidence against it).
// R27 design: R25 structure with the z3 ATOMIC reduction replaced by PRIVATE
// partial writes. R26 post-mortem: L2's 262K contended device-scope fp32
// atomicAdds are far-RMWs at the coherence point (per-XCD L2s non-coherent)
// — FETCH 16.5MB/WRITE 8.3MB of pure atomic traffic — and R26's added
// __threadfence() made every block wait for its 256 contended RMWs to
// drain: L2 30 -> 172 us (MfmaUtil 5.7%). Fix: each L2 block stores its
// 2x128 partial dots to z3p[bt][ot][j][t] (1 KB contiguous, line-private,
// no sharing, no fence; kernel boundary orders). scan3 sums the 16
// ot-partials (1 MB L2-resident) and runs the 128 final leaky-IF scans.
// R25 recap (212.7 us, absmax 0.0): L3 fused into L2 epilogue (ballot mask
// -> per-t partial dot with W3 slice); prep transpose bank-conflict-free
// swizzle; R19 GEMM core untouched (i8 3-plane W = 2^-8*q1 + 2^-15*q2 +
// 2^-22*q3 exact, mfma_i32_16x16x64_i8 fr=lane&15 q=lane>>4, slot swizzle
// phys=row*8+(u0^(row&7)), 512-thr 128m x 64o, kc=128, XCD-aware remap,
// stage->barrier->MFMA->barrier; R20-R22 proved source-level pipelining
// regresses on this structure; R26 proved fenced atomics are worse).

typedef unsigned short ushort_t;
typedef unsigned int uint_t;
typedef unsigned char uchar_t;
typedef int i32x4 __attribute__((ext_vector_type(4)));

#define S1F 0.00390625f             // 2^-8
#define S2F 3.0517578125e-5f        // 2^-15
#define S3F 2.384185791015625e-7f   // 2^-22

__device__ __forceinline__ void glds16(const uchar_t* g, uchar_t* l) {
  __builtin_amdgcn_global_load_lds(
      (const __attribute__((address_space(1))) uint_t*)g,
      (__attribute__((address_space(3))) uint_t*)l, 16, 0, 0);
}

// ---- prep: W1/W2 -> 3 i8 planes (blocks 0..3071) + spike transpose ---------
__global__ __launch_bounds__(256) void prep(const float* __restrict__ W1,
                                            const float* __restrict__ W2,
                                            const float* __restrict__ spike,
                                            char* __restrict__ w1q1,
                                            char* __restrict__ w1q2,
                                            char* __restrict__ w1q3,
                                            char* __restrict__ w2q1,
                                            char* __restrict__ w2q2,
                                            char* __restrict__ w2q3,
                                            uchar_t* __restrict__ A1) {
  const int tid = threadIdx.x;
  if (blockIdx.x < 3072) {
    const float* W;
    char *p1, *p2, *p3;
    size_t e0;
    if (blockIdx.x < 2048) {
      W = W1; p1 = w1q1; p2 = w1q2; p3 = w1q3;
      e0 = (size_t)blockIdx.x * 1024 + tid * 4;
    } else {
      W = W2; p1 = w2q1; p2 = w2q2; p3 = w2q3;
      e0 = (size_t)(blockIdx.x - 2048) * 1024 + tid * 4;
    }
    float4 w = *(const float4*)(W + e0);
    char4 c1, c2, c3;
    float q, r;
#define QUANT(comp, f1, f2, f3)                    \
    q = rintf((comp) * 256.0f);  f1 = (char)(int)q; \
    r = (comp) - q * S1F;                           \
    q = rintf(r * 32768.0f);     f2 = (char)(int)q; \
    r = r - q * S2F;                                \
    q = rintf(r * 4194304.0f);   f3 = (char)(int)q;
    QUANT(w.x, c1.x, c2.x, c3.x)
    QUANT(w.y, c1.y, c2.y, c3.y)
    QUANT(w.z, c1.z, c2.z, c3.z)
    QUANT(w.w, c1.w, c2.w, c3.w)
#undef QUANT
    *(char4*)(p1 + e0) = c1;
    *(char4*)(p2 + e0) = c2;
    *(char4*)(p3 + e0) = c3;
    return;
  }
  // spike [b][i][t] f32 -> A1 [b*128+t][i] i8 (0/1); swizzled LDS transpose
  __shared__ uchar_t lds8[128 * 128];  // [i][col] words, col = swizzled t-word
  const int bid = blockIdx.x - 3072;   // 0..1023
  const int b = bid >> 4;
  const int i0 = (bid & 15) * 128;
#pragma unroll
  for (int it = 0; it < 16; ++it) {
    int p = it * 256 + tid;
    int i = p >> 5, w = p & 31;        // w = t-word index (4 t per word)
    float4 v = *(const float4*)(spike + ((size_t)b * 2048 + i0 + i) * 128 + w * 4);
    uint_t pk = (v.x != 0.0f ? 1u : 0u) | (v.y != 0.0f ? 1u : 0u) << 8 |
                (v.z != 0.0f ? 1u : 0u) << 16 | (v.w != 0.0f ? 1u : 0u) << 24;
    int col = (w + (i >> 2) + (i & 3) * 8) & 31;   // bank-bijective swizzle
    *(uint_t*)(lds8 + ((size_t)i * 32 + col) * 4) = pk;
  }
  __syncthreads();
#pragma unroll
  for (int it = 0; it < 16; ++it) {
    int p = it * 256 + tid;
    int t = p >> 5, jw = p & 31;       // output uint (4 i-bytes)
    int wt = t >> 2, tb = t & 3;
    uint_t b0 = lds8[(((4 * jw + 0) * 32) + ((wt + jw + 0) & 31)) * 4 + tb];
    uint_t b1 = lds8[(((4 * jw + 1) * 32) + ((wt + jw + 8) & 31)) * 4 + tb];
    uint_t b2 = lds8[(((4 * jw + 2) * 32) + ((wt + jw + 16) & 31)) * 4 + tb];
    uint_t b3 = lds8[(((4 * jw + 3) * 32) + ((wt + jw + 24) & 31)) * 4 + tb];
    uint_t u = b0 | (b1 << 8) | (b2 << 16) | (b3 << 24);
    *(uint_t*)(A1 + (size_t)(b * 128 + t) * 2048 + i0 + jw * 4) = u;
  }
}

// ---- fused GEMM (128m x 64o, kc=128B, 512 thr, i8 3-plane) + scan ----------
// S != null: write spikes to S (L1). S == null: fused L3 partial-dot path
// (ballot mask -> per-t dot with W3 slice -> PRIVATE store to
// z3p[bt][ot][j][t], line-private per block, no atomics).
__global__ __launch_bounds__(512, 4)
void gemm_scan(const uchar_t* __restrict__ A, const char* __restrict__ Q1,
               const char* __restrict__ Q2, const char* __restrict__ Q3,
               uchar_t* __restrict__ S, int K, float* __restrict__ z3p,
               const float* __restrict__ W3) {
  __shared__ float smemf[10240];     // 40,960 B staging; Zt overlay 33,280 B
  uchar_t* sA = (uchar_t*)smemf;     // A: slots 0..1023; B plane p: 1024+p*512
  float* Zt = smemf;                 // [128 t][65] epilogue overlay

  const int tid = threadIdx.x;
  const int wave = tid >> 6, lane = tid & 63;
  // XCD-aware remap (grid 16 x 64): XCD ~= bx%8 owns b-tiles [8c, 8c+8)
  const int bt = (blockIdx.x & 7) * 8 + (blockIdx.y & 7);          // 0..63
  const int ot = (blockIdx.x >> 3) * 8 + (blockIdx.y >> 3);        // 0..15
  const int m0 = bt * 128;
  const int o0 = ot * 64;
  const int qm = wave >> 2, qn = wave & 3;
  const int fr = lane & 15, q = lane >> 4;

  i32x4 acc[4][3];
#pragma unroll
  for (int i = 0; i < 4; ++i)
#pragma unroll
    for (int p = 0; p < 3; ++p) acc[i][p] = (i32x4){0, 0, 0, 0};

  // staging: 2560 slots (A 1024 + B 3x512), exactly 5 rounds of 512 threads.
  const char* qplanes[3] = {Q1, Q2, Q3};
  const uchar_t* gsrc[5];
  uchar_t* ldst[5];
#pragma unroll
  for (int it = 0; it < 5; ++it) {
    int s = it * 512 + tid;
    ldst[it] = sA + (size_t)(it * 512 + wave * 64) * 16;
    if (s < 1024) {
      int row = s >> 3;
      int u0 = (s & 7) ^ (row & 7);
      gsrc[it] = A + (size_t)(m0 + row) * K + u0 * 16;
    } else {
      int t2 = s - 1024;
      int p = t2 >> 9, w = t2 & 511;
      int row = w >> 3;
      int u0 = (w & 7) ^ (row & 7);
      gsrc[it] = (const uchar_t*)qplanes[p] + (size_t)(o0 + row) * K + u0 * 16;
    }
  }

  // frag LDS byte offsets per k-half hh: u0 = hh*4 + q
  int aoff[4][2], boff[3][2];  // [p][hh]
#pragma unroll
  for (int i = 0; i < 4; ++i) {
    int row = qm * 64 + i * 16 + fr;
#pragma unroll
    for (int hh = 0; hh < 2; ++hh)
      aoff[i][hh] = (row * 8 + ((hh * 4 + q) ^ (row & 7))) * 16;
  }
  {
    int row = qn * 16 + fr;
#pragma unroll
    for (int hh = 0; hh < 2; ++hh) {
      int rel = row * 8 + ((hh * 4 + q) ^ (row & 7));
#pragma unroll
      for (int p = 0; p < 3; ++p)
        boff[p][hh] = (1024 + p * 512 + rel) * 16;
    }
  }

  for (int kc = 0; kc < K; kc += 128) {
#pragma unroll
    for (int it = 0; it < 5; ++it) glds16(gsrc[it] + kc, ldst[it]);
    __syncthreads();

#pragma unroll
    for (int hh = 0; hh < 2; ++hh) {
      i32x4 af[4], bq[3];
#pragma unroll
      for (int i = 0; i < 4; ++i) af[i] = *(const i32x4*)(sA + aoff[i][hh]);
#pragma unroll
      for (int p = 0; p < 3; ++p) bq[p] = *(const i32x4*)(sA + boff[p][hh]);
#pragma unroll
      for (int p = 0; p < 3; ++p)
#pragma unroll
        for (int i = 0; i < 4; ++i)
          acc[i][p] = __builtin_amdgcn_mfma_i32_16x16x64_i8(af[i], bq[p], acc[i][p], 0, 0, 0);
    }
    __syncthreads();
  }

  // combine planes -> fp32, write Z-tile (C/D: col=fr, row=q*4+rr)
#pragma unroll
  for (int i = 0; i < 4; ++i)
#pragma unroll
    for (int rr = 0; rr < 4; ++rr) {
      int t = qm * 64 + i * 16 + q * 4 + rr;
      float z = (float)acc[i][0][rr] * S1F + (float)acc[i][1][rr] * S2F +
                (float)acc[i][2][rr] * S3F;
      Zt[t * 65 + qn * 16 + fr] = z;
    }
  __syncthreads();

  if (S) {
    // L1: fused leaky-IF scan, write spike plane
    if (tid < 64) {
#pragma clang fp contract(off)
      float cur = 0.0f, vol = 0.0f;
      const int o = o0 + tid;
      for (int t = 0; t < 128; ++t) {
        float z = Zt[t * 65 + tid];
        cur = cur * 0.7f;
        cur = cur + z;
        vol = vol * 0.2f;
        vol = vol + cur;
        float v = vol - 1.0f;
        float s = (v >= 0.0f) ? 1.0f : 0.0f;
        vol = vol * (1.0f - s);
        S[(size_t)(m0 + t) * 1024 + o] = (v >= 0.0f) ? 1u : 0u;
      }
    }
  } else {
    // L2: fused scan + L3 partial dot. masks at float-ofs 8320 (1 KB),
    // W3 slice at 8576 (128 floats) — both beyond Zt's 8320 floats.
    unsigned long long* masks = (unsigned long long*)(smemf + 8320);
    float* w3s = smemf + 8576;
    if (tid < 64) {
#pragma clang fp contract(off)
      float cur = 0.0f, vol = 0.0f;
      for (int t = 0; t < 128; ++t) {
        float z = Zt[t * 65 + tid];
        cur = cur * 0.7f;
        cur = cur + z;
        vol = vol * 0.2f;
        vol = vol + cur;
        float v = vol - 1.0f;
        float s = (v >= 0.0f) ? 1.0f : 0.0f;
        vol = vol * (1.0f - s);
        unsigned long long mk = __ballot(v >= 0.0f);
        if (tid == 0) masks[t] = mk;
      }
    } else if (tid < 192) {
      int r = tid - 64;  // r = j*64 + o
      w3s[r] = W3[(r >> 6) * 1024 + o0 + (r & 63)];
    }
    __syncthreads();
    if (tid < 128) {
      unsigned long long mk = masks[tid];
      float p0 = 0.0f, p1 = 0.0f;
#pragma unroll
      for (int o = 0; o < 64; ++o) {
        float bb = ((mk >> o) & 1ull) ? 1.0f : 0.0f;
        p0 = fmaf(bb, w3s[o], p0);
        p1 = fmaf(bb, w3s[64 + o], p1);
      }
      // private, line-aligned 1 KB per block: z3p[bt][ot][j][t]
      size_t base = ((size_t)(bt * 16 + ot) * 2) * 128;
      z3p[base + tid] = p0;          // j=0
      z3p[base + 128 + tid] = p1;    // j=1
    }
  }
}

// ---------- final: sum 16 ot-partials + 128 leaky-IF scans ------------------
__global__ __launch_bounds__(128) void scan3(const float* __restrict__ z3p,
                                             float* __restrict__ out) {
#pragma clang fp contract(off)
  const int tid = threadIdx.x;
  const int b = tid >> 1, j = tid & 1;
  float cur = 0.0f, vol = 0.0f;
  for (int t = 0; t < 128; ++t) {
    float z = 0.0f;
#pragma unroll
    for (int ot = 0; ot < 16; ++ot)
      z += z3p[((size_t)(b * 16 + ot) * 2 + j) * 128 + t];
    cur = cur * 0.7f;
    cur = cur + z;
    vol = vol * 0.2f;
    vol = vol + cur;
    float v = vol - 1.0f;
    float s = (v >= 0.0f) ? 1.0f : 0.0f;
    vol = vol * (1.0f - s);
    out[b * 256 + j * 128 + t] = s;
  }
}

extern "C" void kernel_launch(void* const* d_in, const int* in_sizes, int n_in,
                              void* d_out, int out_size, void* d_ws, size_t ws_size,
                              hipStream_t stream) {
  const float* spike = (const float*)d_in[0];  // [64, 2048, 128]
  const float* W1 = (const float*)d_in[1];     // [1024, 2048]
  const float* W2 = (const float*)d_in[2];     // [1024, 1024]
  const float* W3 = (const float*)d_in[3];     // [2, 1024]
  float* out = (float*)d_out;                  // [64, 2, 128]

  char* ws = (char*)d_ws;
  const size_t MB = 1024 * 1024;
  uchar_t* A1 = (uchar_t*)ws;                  // 16 MB [8192][2048] i8
  uchar_t* S2 = (uchar_t*)(ws + 16 * MB);      // 8 MB  [8192][1024] i8
  float* z3p = (float*)(ws + 24 * MB);         // 1 MB [64][16][2][128] f32
  char* w1q1 = ws + 32 * MB;                   // 2 MB each
  char* w1q2 = ws + 34 * MB;
  char* w1q3 = ws + 36 * MB;
  char* w2q1 = ws + 38 * MB;                   // 1 MB each
  char* w2q2 = ws + 39 * MB;
  char* w2q3 = ws + 40 * MB;

  // blocks 0..2047: W1 quant; 2048..3071: W2 quant; 3072..4095: transpose
  prep<<<4096, 256, 0, stream>>>(W1, W2, spike, w1q1, w1q2, w1q3, w2q1, w2q2,
                                 w2q3, A1);
  // L1: M=8192 (b*128+t), K=2048 B, O=1024 (16 o-tiles of 64), XCD-remapped
  gemm_scan<<<dim3(16, 64), 512, 0, stream>>>(A1, w1q1, w1q2, w1q3, S2, 2048,
                                              nullptr, nullptr);
  // L2 (+ fused L3 partial dots, private stores): K=1024 B
  gemm_scan<<<dim3(16, 64), 512, 0, stream>>>(S2, w2q1, w2q2, w2q3, nullptr,
                                              1024, z3p, W3);
  // final: sum partials + 128 leaky-IF scans
  scan3<<<1, 128, 0, stream>>>(z3p, out);
}

// Round 10
// 201.800 us; speedup vs baseline: 1.6901x; 1.6901x over previous
//
#include <hip/hip_runtime.h>

// SLAYER 3-layer CUBA SNN — i8 3-plane MFMA GEMM + fused leaky-IF scan.
// R29 = R28 with scan3 parallelized/coalesced. R28 counters: scan3 = 146 us
// (43% of total!) — 1 block, lane-uncoalesced 16-way gather (stride 4096
// floats across lanes -> ~64 cachelines per wave-load, 2048 such loads,
// latency-serialized on one CU; MfmaUtil/VALUBusy ~0). Fix: 128 blocks
// (one per (b,j) scan) x 128 threads (one per t); each thread ot-sums via
// 16 COALESCED wave-loads (fixed (b,j,ot): lanes t read consecutive
// floats), z[t] -> LDS, thread 0 runs the 128-step leaky-IF scan from LDS.
// Ascending-ot summation order preserved -> bit-identical to R28 (absmax
// 0.0). L2's private z3p stores (R27 fix for the atomic far-RMW disaster
// R26 exposed) unchanged; R19 GEMM core unchanged (i8 3-plane W = 2^-8*q1
// + 2^-15*q2 + 2^-22*q3 exact, mfma_i32_16x16x64_i8 fr=lane&15 q=lane>>4,
// slot swizzle phys=row*8+(u0^(row&7)), 512-thr 128m x 64o, kc=128,
// XCD-aware remap, stage->barrier->MFMA->barrier; R20-R22: source-level
// pipelining regresses; R26: fenced contended atomics catastrophic).

typedef unsigned short ushort_t;
typedef unsigned int uint_t;
typedef unsigned char uchar_t;
typedef int i32x4 __attribute__((ext_vector_type(4)));

#define S1F 0.00390625f             // 2^-8
#define S2F 3.0517578125e-5f        // 2^-15
#define S3F 2.384185791015625e-7f   // 2^-22

__device__ __forceinline__ void glds16(const uchar_t* g, uchar_t* l) {
  __builtin_amdgcn_global_load_lds(
      (const __attribute__((address_space(1))) uint_t*)g,
      (__attribute__((address_space(3))) uint_t*)l, 16, 0, 0);
}

// ---- prep: W1/W2 -> 3 i8 planes (blocks 0..3071) + spike transpose ---------
__global__ __launch_bounds__(256) void prep(const float* __restrict__ W1,
                                            const float* __restrict__ W2,
                                            const float* __restrict__ spike,
                                            char* __restrict__ w1q1,
                                            char* __restrict__ w1q2,
                                            char* __restrict__ w1q3,
                                            char* __restrict__ w2q1,
                                            char* __restrict__ w2q2,
                                            char* __restrict__ w2q3,
                                            uchar_t* __restrict__ A1) {
  const int tid = threadIdx.x;
  if (blockIdx.x < 3072) {
    const float* W;
    char *p1, *p2, *p3;
    size_t e0;
    if (blockIdx.x < 2048) {
      W = W1; p1 = w1q1; p2 = w1q2; p3 = w1q3;
      e0 = (size_t)blockIdx.x * 1024 + tid * 4;
    } else {
      W = W2; p1 = w2q1; p2 = w2q2; p3 = w2q3;
      e0 = (size_t)(blockIdx.x - 2048) * 1024 + tid * 4;
    }
    float4 w = *(const float4*)(W + e0);
    char4 c1, c2, c3;
    float q, r;
#define QUANT(comp, f1, f2, f3)                    \
    q = rintf((comp) * 256.0f);  f1 = (char)(int)q; \
    r = (comp) - q * S1F;                           \
    q = rintf(r * 32768.0f);     f2 = (char)(int)q; \
    r = r - q * S2F;                                \
    q = rintf(r * 4194304.0f);   f3 = (char)(int)q;
    QUANT(w.x, c1.x, c2.x, c3.x)
    QUANT(w.y, c1.y, c2.y, c3.y)
    QUANT(w.z, c1.z, c2.z, c3.z)
    QUANT(w.w, c1.w, c2.w, c3.w)
#undef QUANT
    *(char4*)(p1 + e0) = c1;
    *(char4*)(p2 + e0) = c2;
    *(char4*)(p3 + e0) = c3;
    return;
  }
  // spike [b][i][t] f32 -> A1 [b*128+t][i] i8 (0/1); swizzled LDS transpose
  __shared__ uchar_t lds8[128 * 128];  // [i][col] words, col = swizzled t-word
  const int bid = blockIdx.x - 3072;   // 0..1023
  const int b = bid >> 4;
  const int i0 = (bid & 15) * 128;
#pragma unroll
  for (int it = 0; it < 16; ++it) {
    int p = it * 256 + tid;
    int i = p >> 5, w = p & 31;        // w = t-word index (4 t per word)
    float4 v = *(const float4*)(spike + ((size_t)b * 2048 + i0 + i) * 128 + w * 4);
    uint_t pk = (v.x != 0.0f ? 1u : 0u) | (v.y != 0.0f ? 1u : 0u) << 8 |
                (v.z != 0.0f ? 1u : 0u) << 16 | (v.w != 0.0f ? 1u : 0u) << 24;
    int col = (w + (i >> 2) + (i & 3) * 8) & 31;   // bank-bijective swizzle
    *(uint_t*)(lds8 + ((size_t)i * 32 + col) * 4) = pk;
  }
  __syncthreads();
#pragma unroll
  for (int it = 0; it < 16; ++it) {
    int p = it * 256 + tid;
    int t = p >> 5, jw = p & 31;       // output uint (4 i-bytes)
    int wt = t >> 2, tb = t & 3;
    uint_t b0 = lds8[(((4 * jw + 0) * 32) + ((wt + jw + 0) & 31)) * 4 + tb];
    uint_t b1 = lds8[(((4 * jw + 1) * 32) + ((wt + jw + 8) & 31)) * 4 + tb];
    uint_t b2 = lds8[(((4 * jw + 2) * 32) + ((wt + jw + 16) & 31)) * 4 + tb];
    uint_t b3 = lds8[(((4 * jw + 3) * 32) + ((wt + jw + 24) & 31)) * 4 + tb];
    uint_t u = b0 | (b1 << 8) | (b2 << 16) | (b3 << 24);
    *(uint_t*)(A1 + (size_t)(b * 128 + t) * 2048 + i0 + jw * 4) = u;
  }
}

// ---- fused GEMM (128m x 64o, kc=128B, 512 thr, i8 3-plane) + scan ----------
// S != null: write spikes to S (L1). S == null: fused L3 partial-dot path
// (ballot mask -> per-t dot with W3 slice -> PRIVATE store to
// z3p[bt][ot][j][t], line-private per block, no atomics).
__global__ __launch_bounds__(512, 4)
void gemm_scan(const uchar_t* __restrict__ A, const char* __restrict__ Q1,
               const char* __restrict__ Q2, const char* __restrict__ Q3,
               uchar_t* __restrict__ S, int K, float* __restrict__ z3p,
               const float* __restrict__ W3) {
  __shared__ float smemf[10240];     // 40,960 B staging; Zt overlay 33,280 B
  uchar_t* sA = (uchar_t*)smemf;     // A: slots 0..1023; B plane p: 1024+p*512
  float* Zt = smemf;                 // [128 t][65] epilogue overlay

  const int tid = threadIdx.x;
  const int wave = tid >> 6, lane = tid & 63;
  // XCD-aware remap (grid 16 x 64): XCD ~= bx%8 owns b-tiles [8c, 8c+8)
  const int bt = (blockIdx.x & 7) * 8 + (blockIdx.y & 7);          // 0..63
  const int ot = (blockIdx.x >> 3) * 8 + (blockIdx.y >> 3);        // 0..15
  const int m0 = bt * 128;
  const int o0 = ot * 64;
  const int qm = wave >> 2, qn = wave & 3;
  const int fr = lane & 15, q = lane >> 4;

  i32x4 acc[4][3];
#pragma unroll
  for (int i = 0; i < 4; ++i)
#pragma unroll
    for (int p = 0; p < 3; ++p) acc[i][p] = (i32x4){0, 0, 0, 0};

  // staging: 2560 slots (A 1024 + B 3x512), exactly 5 rounds of 512 threads.
  const char* qplanes[3] = {Q1, Q2, Q3};
  const uchar_t* gsrc[5];
  uchar_t* ldst[5];
#pragma unroll
  for (int it = 0; it < 5; ++it) {
    int s = it * 512 + tid;
    ldst[it] = sA + (size_t)(it * 512 + wave * 64) * 16;
    if (s < 1024) {
      int row = s >> 3;
      int u0 = (s & 7) ^ (row & 7);
      gsrc[it] = A + (size_t)(m0 + row) * K + u0 * 16;
    } else {
      int t2 = s - 1024;
      int p = t2 >> 9, w = t2 & 511;
      int row = w >> 3;
      int u0 = (w & 7) ^ (row & 7);
      gsrc[it] = (const uchar_t*)qplanes[p] + (size_t)(o0 + row) * K + u0 * 16;
    }
  }

  // frag LDS byte offsets per k-half hh: u0 = hh*4 + q
  int aoff[4][2], boff[3][2];  // [p][hh]
#pragma unroll
  for (int i = 0; i < 4; ++i) {
    int row = qm * 64 + i * 16 + fr;
#pragma unroll
    for (int hh = 0; hh < 2; ++hh)
      aoff[i][hh] = (row * 8 + ((hh * 4 + q) ^ (row & 7))) * 16;
  }
  {
    int row = qn * 16 + fr;
#pragma unroll
    for (int hh = 0; hh < 2; ++hh) {
      int rel = row * 8 + ((hh * 4 + q) ^ (row & 7));
#pragma unroll
      for (int p = 0; p < 3; ++p)
        boff[p][hh] = (1024 + p * 512 + rel) * 16;
    }
  }

  for (int kc = 0; kc < K; kc += 128) {
#pragma unroll
    for (int it = 0; it < 5; ++it) glds16(gsrc[it] + kc, ldst[it]);
    __syncthreads();

#pragma unroll
    for (int hh = 0; hh < 2; ++hh) {
      i32x4 af[4], bq[3];
#pragma unroll
      for (int i = 0; i < 4; ++i) af[i] = *(const i32x4*)(sA + aoff[i][hh]);
#pragma unroll
      for (int p = 0; p < 3; ++p) bq[p] = *(const i32x4*)(sA + boff[p][hh]);
#pragma unroll
      for (int p = 0; p < 3; ++p)
#pragma unroll
        for (int i = 0; i < 4; ++i)
          acc[i][p] = __builtin_amdgcn_mfma_i32_16x16x64_i8(af[i], bq[p], acc[i][p], 0, 0, 0);
    }
    __syncthreads();
  }

  // combine planes -> fp32, write Z-tile (C/D: col=fr, row=q*4+rr)
#pragma unroll
  for (int i = 0; i < 4; ++i)
#pragma unroll
    for (int rr = 0; rr < 4; ++rr) {
      int t = qm * 64 + i * 16 + q * 4 + rr;
      float z = (float)acc[i][0][rr] * S1F + (float)acc[i][1][rr] * S2F +
                (float)acc[i][2][rr] * S3F;
      Zt[t * 65 + qn * 16 + fr] = z;
    }
  __syncthreads();

  if (S) {
    // L1: fused leaky-IF scan, write spike plane
    if (tid < 64) {
#pragma clang fp contract(off)
      float cur = 0.0f, vol = 0.0f;
      const int o = o0 + tid;
      for (int t = 0; t < 128; ++t) {
        float z = Zt[t * 65 + tid];
        cur = cur * 0.7f;
        cur = cur + z;
        vol = vol * 0.2f;
        vol = vol + cur;
        float v = vol - 1.0f;
        float s = (v >= 0.0f) ? 1.0f : 0.0f;
        vol = vol * (1.0f - s);
        S[(size_t)(m0 + t) * 1024 + o] = (v >= 0.0f) ? 1u : 0u;
      }
    }
  } else {
    // L2: fused scan + L3 partial dot. masks at float-ofs 8320 (1 KB),
    // W3 slice at 8576 (128 floats) — both beyond Zt's 8320 floats.
    unsigned long long* masks = (unsigned long long*)(smemf + 8320);
    float* w3s = smemf + 8576;
    if (tid < 64) {
#pragma clang fp contract(off)
      float cur = 0.0f, vol = 0.0f;
      for (int t = 0; t < 128; ++t) {
        float z = Zt[t * 65 + tid];
        cur = cur * 0.7f;
        cur = cur + z;
        vol = vol * 0.2f;
        vol = vol + cur;
        float v = vol - 1.0f;
        float s = (v >= 0.0f) ? 1.0f : 0.0f;
        vol = vol * (1.0f - s);
        unsigned long long mk = __ballot(v >= 0.0f);
        if (tid == 0) masks[t] = mk;
      }
    } else if (tid < 192) {
      int r = tid - 64;  // r = j*64 + o
      w3s[r] = W3[(r >> 6) * 1024 + o0 + (r & 63)];
    }
    __syncthreads();
    if (tid < 128) {
      unsigned long long mk = masks[tid];
      float p0 = 0.0f, p1 = 0.0f;
#pragma unroll
      for (int o = 0; o < 64; ++o) {
        float bb = ((mk >> o) & 1ull) ? 1.0f : 0.0f;
        p0 = fmaf(bb, w3s[o], p0);
        p1 = fmaf(bb, w3s[64 + o], p1);
      }
      // private, line-aligned 1 KB per block: z3p[bt][ot][j][t]
      size_t base = ((size_t)(bt * 16 + ot) * 2) * 128;
      z3p[base + tid] = p0;          // j=0
      z3p[base + 128 + tid] = p1;    // j=1
    }
  }
}

// ---------- final: 128 blocks, coalesced ot-sum + leaky-IF scan -------------
// block = b*2+j; thread = t. 16 coalesced wave-loads per block (fixed
// (b,j,ot): lanes t read 128 consecutive floats); z[t] -> LDS; thread 0
// runs the serial 128-step scan from LDS. Ascending-ot order preserved.
__global__ __launch_bounds__(128) void scan3(const float* __restrict__ z3p,
                                             float* __restrict__ out) {
  __shared__ float zs[128];
  const int b = blockIdx.x >> 1, j = blockIdx.x & 1;
  const int t = threadIdx.x;
  float z = 0.0f;
#pragma unroll
  for (int ot = 0; ot < 16; ++ot)
    z += z3p[((size_t)(b * 16 + ot) * 2 + j) * 128 + t];
  zs[t] = z;
  __syncthreads();
  if (t == 0) {
#pragma clang fp contract(off)
    float cur = 0.0f, vol = 0.0f;
    for (int tt = 0; tt < 128; ++tt) {
      float zz = zs[tt];
      cur = cur * 0.7f;
      cur = cur + zz;
      vol = vol * 0.2f;
      vol = vol + cur;
      float v = vol - 1.0f;
      float s = (v >= 0.0f) ? 1.0f : 0.0f;
      vol = vol * (1.0f - s);
      out[b * 256 + j * 128 + tt] = s;
    }
  }
}

extern "C" void kernel_launch(void* const* d_in, const int* in_sizes, int n_in,
                              void* d_out, int out_size, void* d_ws, size_t ws_size,
                              hipStream_t stream) {
  const float* spike = (const float*)d_in[0];  // [64, 2048, 128]
  const float* W1 = (const float*)d_in[1];     // [1024, 2048]
  const float* W2 = (const float*)d_in[2];     // [1024, 1024]
  const float* W3 = (const float*)d_in[3];     // [2, 1024]
  float* out = (float*)d_out;                  // [64, 2, 128]

  char* ws = (char*)d_ws;
  const size_t MB = 1024 * 1024;
  uchar_t* A1 = (uchar_t*)ws;                  // 16 MB [8192][2048] i8
  uchar_t* S2 = (uchar_t*)(ws + 16 * MB);      // 8 MB  [8192][1024] i8
  float* z3p = (float*)(ws + 24 * MB);         // 1 MB [64][16][2][128] f32
  char* w1q1 = ws + 32 * MB;                   // 2 MB each
  char* w1q2 = ws + 34 * MB;
  char* w1q3 = ws + 36 * MB;
  char* w2q1 = ws + 38 * MB;                   // 1 MB each
  char* w2q2 = ws + 39 * MB;
  char* w2q3 = ws + 40 * MB;

  // blocks 0..2047: W1 quant; 2048..3071: W2 quant; 3072..4095: transpose
  prep<<<4096, 256, 0, stream>>>(W1, W2, spike, w1q1, w1q2, w1q3, w2q1, w2q2,
                                 w2q3, A1);
  // L1: M=8192 (b*128+t), K=2048 B, O=1024 (16 o-tiles of 64), XCD-remapped
  gemm_scan<<<dim3(16, 64), 512, 0, stream>>>(A1, w1q1, w1q2, w1q3, S2, 2048,
                                              nullptr, nullptr);
  // L2 (+ fused L3 partial dots, private stores): K=1024 B
  gemm_scan<<<dim3(16, 64), 512, 0, stream>>>(S2, w2q1, w2q2, w2q3, nullptr,
                                              1024, z3p, W3);
  // final: coalesced partial-sum + 128 leaky-IF scans (128 blocks)
  scan3<<<128, 128, 0, stream>>>(z3p, out);
}